// Round 3
// baseline (532.233 us; speedup 1.0000x reference)
//
#include <hip/hip_runtime.h>
#include <hip/hip_bf16.h>
#include <cstdint>
#include <cstddef>

typedef __bf16 bf16;
typedef __bf16 bf16x8 __attribute__((ext_vector_type(8)));
typedef __bf16 bf16x4 __attribute__((ext_vector_type(4)));
typedef float f32x4 __attribute__((ext_vector_type(4)));

static constexpr int BATCH = 2;
static constexpr int SEQ = 2048;
static constexpr int DMODEL = 2048;
static constexpr int NH = 16;
static constexpr int HD = 128;
static constexpr int MROWS = BATCH * SEQ; // 4096

#define GLOBAL_AS(p) ((const __attribute__((address_space(1))) void*)(p))
#define LDS_AS(p)    ((__attribute__((address_space(3))) void*)(p))

// ---------------- fp32 -> bf16 convert ----------------
__global__ void cvt_kernel(const float* __restrict__ src, bf16* __restrict__ dst, int n4) {
  int i = blockIdx.x * blockDim.x + threadIdx.x;
  if (i < n4) {
    float4 f = reinterpret_cast<const float4*>(src)[i];
    bf16x4 o;
    o.x = (bf16)f.x; o.y = (bf16)f.y; o.z = (bf16)f.z; o.w = (bf16)f.w;
    reinterpret_cast<bf16x4*>(dst)[i] = o;
  }
}

// ---------------- GEMM: C = A(MxK,row) * W(NxK,row)^T, m97 structure ----------------
enum { MODE_QKV = 0, MODE_OUT = 1 };

template <int MODE>
__global__ __launch_bounds__(256, 2) void gemm_bt(
    const bf16* __restrict__ A, const bf16* __restrict__ W,
    bf16* __restrict__ Oq, bf16* __restrict__ Ok, bf16* __restrict__ Ov,
    float* __restrict__ Oout) {
  constexpr int Kd = DMODEL;
  __shared__ __align__(16) bf16 As[128][64];
  __shared__ __align__(16) bf16 Bs[128][64];
  const int n0 = blockIdx.x * 128;
  const int m0 = blockIdx.y * 128;
  const int tid = threadIdx.x;
  const int wave = tid >> 6;
  const int lane = tid & 63;
  const int quad = lane >> 4;
  const int l16 = lane & 15;
  const int wm = (wave >> 1) * 64;
  const int wn = (wave & 1) * 64;
  const int sr = lane >> 3;
  const int sc = (lane & 7) * 8;

  f32x4 acc[4][4] = {};
  for (int kt = 0; kt < Kd; kt += 64) {
#pragma unroll
    for (int i = 0; i < 4; i++) {
      const int r = wave * 32 + i * 8;
      __builtin_amdgcn_global_load_lds(
          GLOBAL_AS(&A[(size_t)(m0 + r + sr) * Kd + kt + sc]), LDS_AS(&As[r][0]), 16, 0, 0);
      __builtin_amdgcn_global_load_lds(
          GLOBAL_AS(&W[(size_t)(n0 + r + sr) * Kd + kt + sc]), LDS_AS(&Bs[r][0]), 16, 0, 0);
    }
    __syncthreads();
#pragma unroll
    for (int ks = 0; ks < 2; ks++) {
      bf16x8 af[4], bfr[4];
#pragma unroll
      for (int t = 0; t < 4; t++)
        af[t] = *reinterpret_cast<const bf16x8*>(&As[wm + t * 16 + l16][ks * 32 + quad * 8]);
#pragma unroll
      for (int t = 0; t < 4; t++)
        bfr[t] = *reinterpret_cast<const bf16x8*>(&Bs[wn + t * 16 + l16][ks * 32 + quad * 8]);
#pragma unroll
      for (int tm = 0; tm < 4; tm++)
#pragma unroll
        for (int tn = 0; tn < 4; tn++)
          acc[tm][tn] = __builtin_amdgcn_mfma_f32_16x16x32_bf16(af[tm], bfr[tn], acc[tm][tn], 0, 0, 0);
    }
    __syncthreads();
  }
#pragma unroll
  for (int tm = 0; tm < 4; tm++) {
#pragma unroll
    for (int tn = 0; tn < 4; tn++) {
      const int row0 = m0 + wm + tm * 16 + quad * 4;
      if constexpr (MODE == MODE_OUT) {
        const int col = n0 + wn + tn * 16 + l16;
#pragma unroll
        for (int j = 0; j < 4; j++)
          Oout[(size_t)(row0 + j) * DMODEL + col] = acc[tm][tn][j];
      } else {
        const int mat = n0 >> 11;              // 0=Q 1=K 2=V
        const int col = (n0 & 2047) + wn + tn * 16 + l16;
        const int h = col >> 7, dd = col & 127;
        if (mat == 2) {
          const int b = row0 >> 11, s = row0 & 2047;
          bf16x4 pk;
#pragma unroll
          for (int j = 0; j < 4; j++) pk[j] = (bf16)acc[tm][tn][j];
          *reinterpret_cast<bf16x4*>(&Ov[((size_t)(b * NH + h) * HD + dd) * SEQ + s]) = pk;
        } else {
          bf16* O = mat ? Ok : Oq;
          const float scale = mat ? 1.0f : 0.08838834764831845f;
#pragma unroll
          for (int j = 0; j < 4; j++) {
            const int row = row0 + j;
            const int b = row >> 11, s = row & 2047;
            O[((size_t)(b * NH + h) * SEQ + s) * HD + dd] = (bf16)(acc[tm][tn][j] * scale);
          }
        }
      }
    }
  }
}

// ---------------- flash attention, S^T formulation, q-tile 64 ----------------
// grid (32 qt, 32 bh) = 1024 blocks; block 256 = 4 waves; wave owns 16 q-rows.
// 2 barriers/tile; Ps per-wave (no cross-wave dep); global_load_lds staging.
// LDS: Ks 16K + Vts 16K + Ps 9.2K = 41.9 KB -> 3 blocks/CU.
__global__ __launch_bounds__(256, 3) void attn_kernel(
    const bf16* __restrict__ Q, const bf16* __restrict__ K,
    const bf16* __restrict__ Vt, bf16* __restrict__ Y) {
  const int qt = 31 - (int)blockIdx.x;     // longest blocks launch first
  const int bh = blockIdx.y;
  const int q0 = qt * 64;
  __shared__ __align__(16) char smem[41984];
  auto Ks  = (bf16(*)[128])smem;               // [64][128]  16384 B (unpadded, glds)
  auto Vts = (bf16(*)[64])(smem + 16384);      // [128][64]  16384 B (unpadded, glds)
  auto Ps  = (bf16(*)[16][72])(smem + 32768);  // [4][16][72] 9216 B (padded, per-wave)
  const int tid = threadIdx.x;
  const int wave = tid >> 6;
  const int lane = tid & 63;
  const int quad = lane >> 4;
  const int l16 = lane & 15;

  // Q fragments (B-operand: B[k=d][n=q] = Q[q][d]) in registers; q = wave*16+l16
  const bf16* Qw = Q + ((size_t)bh * SEQ + q0 + wave * 16) * HD;
  bf16x8 qf[4];
#pragma unroll
  for (int kk = 0; kk < 4; kk++)
    qf[kk] = *reinterpret_cast<const bf16x8*>(&Qw[(size_t)l16 * HD + kk * 32 + quad * 8]);

  f32x4 oacc[8] = {};          // O^T[d = mt8*16+quad*4+j][q = l16]
  float m_i = -3.0e38f, l_i = 0.f;

  const bf16* Kbh = K + (size_t)bh * SEQ * HD;
  const bf16* Vbh = Vt + (size_t)bh * HD * SEQ;
  // per-lane staging coords
  const int krow = lane >> 4, kcol = (lane & 15) * 8;   // K: 4 rows/1KB chunk
  const int vrow = lane >> 3, vcol = (lane & 7) * 8;    // Vt: 8 rows/1KB chunk

  for (int kt = 0; kt <= q0; kt += 64) {
    // ---- async stage K (64x128) and Vt (128x64) ----
#pragma unroll
    for (int i = 0; i < 4; i++) {
      const int r = wave * 16 + i * 4;   // K rows
      __builtin_amdgcn_global_load_lds(
          GLOBAL_AS(&Kbh[(size_t)(kt + r + krow) * HD + kcol]), LDS_AS(&Ks[r][0]), 16, 0, 0);
    }
#pragma unroll
    for (int i = 0; i < 4; i++) {
      const int r = wave * 32 + i * 8;   // Vt rows (d)
      __builtin_amdgcn_global_load_lds(
          GLOBAL_AS(&Vbh[(size_t)(r + vrow) * SEQ + kt + vcol]), LDS_AS(&Vts[r][0]), 16, 0, 0);
    }
    __syncthreads();

    // ---- S^T = K Q^T : sacc[key-tile mt][.] , col = q = l16 ----
    f32x4 sacc[4] = {};
#pragma unroll
    for (int kk = 0; kk < 4; kk++) {
      bf16x8 ka[4];
#pragma unroll
      for (int mt = 0; mt < 4; mt++)
        ka[mt] = *reinterpret_cast<const bf16x8*>(&Ks[mt * 16 + l16][kk * 32 + quad * 8]);
#pragma unroll
      for (int mt = 0; mt < 4; mt++)
        sacc[mt] = __builtin_amdgcn_mfma_f32_16x16x32_bf16(ka[mt], qf[kk], sacc[mt], 0, 0, 0);
    }

    // ---- online softmax; lane holds 16 keys for q = l16; quads hold the rest ----
    const int qg_loc = wave * 16 + l16;    // q within tile; global q = q0 + qg_loc
    float mx = -3.0e38f;
    if (kt == q0) {                        // diagonal tile: mask (block-uniform branch)
#pragma unroll
      for (int mt = 0; mt < 4; mt++)
#pragma unroll
        for (int j = 0; j < 4; j++) {
          const int kg = mt * 16 + quad * 4 + j;   // key within tile
          float v = (kg <= qg_loc) ? sacc[mt][j] : -3.0e38f;
          sacc[mt][j] = v;
          mx = fmaxf(mx, v);
        }
    } else {
#pragma unroll
      for (int mt = 0; mt < 4; mt++)
#pragma unroll
        for (int j = 0; j < 4; j++) mx = fmaxf(mx, sacc[mt][j]);
    }
    mx = fmaxf(mx, __shfl_xor(mx, 16));
    mx = fmaxf(mx, __shfl_xor(mx, 32));
    const float mnew = fmaxf(m_i, mx);
    const float alpha = __expf(m_i - mnew);
    m_i = mnew;
    float rs = 0.f;
#pragma unroll
    for (int mt = 0; mt < 4; mt++)
#pragma unroll
      for (int j = 0; j < 4; j++) {
        float p = __expf(sacc[mt][j] - mnew);
        sacc[mt][j] = p;
        rs += p;
      }
    rs += __shfl_xor(rs, 16);
    rs += __shfl_xor(rs, 32);
    l_i = l_i * alpha + rs;
#pragma unroll
    for (int mt8 = 0; mt8 < 8; mt8++)
#pragma unroll
      for (int j = 0; j < 4; j++) oacc[mt8][j] *= alpha;

    // ---- P^T -> per-wave LDS (B-operand layout: Ps[q][key]) ----
#pragma unroll
    for (int mt = 0; mt < 4; mt++) {
      bf16x4 pk;
#pragma unroll
      for (int j = 0; j < 4; j++) pk[j] = (bf16)sacc[mt][j];
      *reinterpret_cast<bf16x4*>(&Ps[wave][l16][mt * 16 + quad * 4]) = pk;
    }

    // ---- O^T += V^T P^T (A = Vts[d][key], B = Ps[q][key], same-wave Ps) ----
#pragma unroll
    for (int kk2 = 0; kk2 < 2; kk2++) {
      bf16x8 pb = *reinterpret_cast<const bf16x8*>(&Ps[wave][l16][kk2 * 32 + quad * 8]);
#pragma unroll
      for (int mt8 = 0; mt8 < 8; mt8++) {
        bf16x8 av = *reinterpret_cast<const bf16x8*>(&Vts[mt8 * 16 + l16][kk2 * 32 + quad * 8]);
        oacc[mt8] = __builtin_amdgcn_mfma_f32_16x16x32_bf16(av, pb, oacc[mt8], 0, 0, 0);
      }
    }
    __syncthreads();   // all waves done with Ks/Vts before restage
  }

  // ---- epilogue: O^T/l -> Y[b][s][h*128+d] ----
  const int b = bh >> 4, h = bh & 15;
  const float inv = 1.0f / l_i;
  const int qg = q0 + wave * 16 + l16;
#pragma unroll
  for (int mt8 = 0; mt8 < 8; mt8++) {
    bf16x4 pk;
#pragma unroll
    for (int j = 0; j < 4; j++) pk[j] = (bf16)(oacc[mt8][j] * inv);
    *reinterpret_cast<bf16x4*>(
        &Y[(size_t)(b * SEQ + qg) * DMODEL + h * HD + mt8 * 16 + quad * 4]) = pk;
  }
}

// ---------------- launch ----------------
extern "C" void kernel_launch(void* const* d_in, const int* in_sizes, int n_in,
                              void* d_out, int out_size, void* d_ws, size_t ws_size,
                              hipStream_t stream) {
  const float* x  = (const float*)d_in[0];
  const float* Wq = (const float*)d_in[2];
  const float* Wk = (const float*)d_in[3];
  const float* Wv = (const float*)d_in[4];
  const float* Wo = (const float*)d_in[5];
  float* out = (float*)d_out;

  char* ws = (char*)d_ws;
  bf16* xb  = (bf16*)(ws + 0);
  bf16* Wqb = (bf16*)(ws + 16777216);    // Wq,Wk,Wv contiguous -> one [6144][2048]
  bf16* Wkb = (bf16*)(ws + 25165824);
  bf16* Wvb = (bf16*)(ws + 33554432);
  bf16* Wob = (bf16*)(ws + 41943040);
  bf16* Qb  = (bf16*)(ws + 50331648);    // [B,H,S,d]
  bf16* Kb  = (bf16*)(ws + 67108864);    // [B,H,S,d]
  bf16* Vtb = (bf16*)(ws + 83886080);    // [B,H,d,S]
  bf16* Yb  = xb;                        // [B,S,D] (x dead after projections)
  if (ws_size < 100663296) return;

  const int nx4 = MROWS * DMODEL / 4;
  const int nw4 = DMODEL * DMODEL / 4;
  cvt_kernel<<<nx4 / 256, 256, 0, stream>>>(x, xb, nx4);
  cvt_kernel<<<nw4 / 256, 256, 0, stream>>>(Wq, Wqb, nw4);
  cvt_kernel<<<nw4 / 256, 256, 0, stream>>>(Wk, Wkb, nw4);
  cvt_kernel<<<nw4 / 256, 256, 0, stream>>>(Wv, Wvb, nw4);
  cvt_kernel<<<nw4 / 256, 256, 0, stream>>>(Wo, Wob, nw4);

  gemm_bt<MODE_QKV><<<dim3(48, MROWS / 128), 256, 0, stream>>>(
      xb, Wqb, Qb, Kb, Vtb, nullptr);

  attn_kernel<<<dim3(32, BATCH * NH), 256, 0, stream>>>(Qb, Kb, Vtb, Yb);

  gemm_bt<MODE_OUT><<<dim3(16, MROWS / 128), 256, 0, stream>>>(
      Yb, Wob, nullptr, nullptr, nullptr, out);
}

// Round 4
// 396.776 us; speedup vs baseline: 1.3414x; 1.3414x over previous
//
#include <hip/hip_runtime.h>
#include <hip/hip_bf16.h>
#include <cstdint>
#include <cstddef>

typedef __bf16 bf16;
typedef __bf16 bf16x8 __attribute__((ext_vector_type(8)));
typedef __bf16 bf16x4 __attribute__((ext_vector_type(4)));
typedef float f32x4 __attribute__((ext_vector_type(4)));

static constexpr int BATCH = 2;
static constexpr int SEQ = 2048;
static constexpr int DMODEL = 2048;
static constexpr int NH = 16;
static constexpr int HD = 128;
static constexpr int MROWS = BATCH * SEQ; // 4096

#define GLOBAL_AS(p) ((const __attribute__((address_space(1))) void*)(p))
#define LDS_AS(p)    ((__attribute__((address_space(3))) void*)(p))

// ---------------- fp32 -> bf16 convert ----------------
__global__ void cvt_kernel(const float* __restrict__ src, bf16* __restrict__ dst, int n4) {
  int i = blockIdx.x * blockDim.x + threadIdx.x;
  if (i < n4) {
    float4 f = reinterpret_cast<const float4*>(src)[i];
    bf16x4 o;
    o.x = (bf16)f.x; o.y = (bf16)f.y; o.z = (bf16)f.z; o.w = (bf16)f.w;
    reinterpret_cast<bf16x4*>(dst)[i] = o;
  }
}

// ---------------- GEMM: C = A(MxK,row) * W(NxK,row)^T, m97 structure ----------------
enum { MODE_QKV = 0, MODE_OUT = 1 };

template <int MODE>
__global__ __launch_bounds__(256, 2) void gemm_bt(
    const bf16* __restrict__ A, const bf16* __restrict__ W,
    bf16* __restrict__ Oq, bf16* __restrict__ Ok, bf16* __restrict__ Ov,
    float* __restrict__ Oout) {
  constexpr int Kd = DMODEL;
  __shared__ __align__(16) bf16 As[128][64];
  __shared__ __align__(16) bf16 Bs[128][64];
  const int n0 = blockIdx.x * 128;
  const int m0 = blockIdx.y * 128;
  const int tid = threadIdx.x;
  const int wave = tid >> 6;
  const int lane = tid & 63;
  const int quad = lane >> 4;
  const int l16 = lane & 15;
  const int wm = (wave >> 1) * 64;
  const int wn = (wave & 1) * 64;
  const int sr = lane >> 3;
  const int sc = (lane & 7) * 8;

  f32x4 acc[4][4] = {};
  for (int kt = 0; kt < Kd; kt += 64) {
#pragma unroll
    for (int i = 0; i < 4; i++) {
      const int r = wave * 32 + i * 8;
      __builtin_amdgcn_global_load_lds(
          GLOBAL_AS(&A[(size_t)(m0 + r + sr) * Kd + kt + sc]), LDS_AS(&As[r][0]), 16, 0, 0);
      __builtin_amdgcn_global_load_lds(
          GLOBAL_AS(&W[(size_t)(n0 + r + sr) * Kd + kt + sc]), LDS_AS(&Bs[r][0]), 16, 0, 0);
    }
    __syncthreads();
#pragma unroll
    for (int ks = 0; ks < 2; ks++) {
      bf16x8 af[4], bfr[4];
#pragma unroll
      for (int t = 0; t < 4; t++)
        af[t] = *reinterpret_cast<const bf16x8*>(&As[wm + t * 16 + l16][ks * 32 + quad * 8]);
#pragma unroll
      for (int t = 0; t < 4; t++)
        bfr[t] = *reinterpret_cast<const bf16x8*>(&Bs[wn + t * 16 + l16][ks * 32 + quad * 8]);
#pragma unroll
      for (int tm = 0; tm < 4; tm++)
#pragma unroll
        for (int tn = 0; tn < 4; tn++)
          acc[tm][tn] = __builtin_amdgcn_mfma_f32_16x16x32_bf16(af[tm], bfr[tn], acc[tm][tn], 0, 0, 0);
    }
    __syncthreads();
  }
#pragma unroll
  for (int tm = 0; tm < 4; tm++) {
#pragma unroll
    for (int tn = 0; tn < 4; tn++) {
      const int row0 = m0 + wm + tm * 16 + quad * 4;
      if constexpr (MODE == MODE_OUT) {
        const int col = n0 + wn + tn * 16 + l16;
#pragma unroll
        for (int j = 0; j < 4; j++)
          Oout[(size_t)(row0 + j) * DMODEL + col] = acc[tm][tn][j];
      } else {
        const int mat = n0 >> 11;              // 0=Q 1=K 2=V
        const int col = (n0 & 2047) + wn + tn * 16 + l16;
        const int h = col >> 7, dd = col & 127;
        if (mat == 2) {
          const int b = row0 >> 11, s = row0 & 2047;
          bf16x4 pk;
#pragma unroll
          for (int j = 0; j < 4; j++) pk[j] = (bf16)acc[tm][tn][j];
          *reinterpret_cast<bf16x4*>(&Ov[((size_t)(b * NH + h) * HD + dd) * SEQ + s]) = pk;
        } else {
          bf16* O = mat ? Ok : Oq;
          const float scale = mat ? 1.0f : 0.08838834764831845f;
#pragma unroll
          for (int j = 0; j < 4; j++) {
            const int row = row0 + j;
            const int b = row >> 11, s = row & 2047;
            O[((size_t)(b * NH + h) * SEQ + s) * HD + dd] = (bf16)(acc[tm][tn][j] * scale);
          }
        }
      }
    }
  }
}

// ---------------- flash attention ----------------
// Triangle-folded: block (j, bh) processes q-tiles qt=j AND qt=31-j -> every
// block does exactly 33 key-tiles (perfect balance). grid (16,32)=512 blocks,
// LDS padded to 54.5 KB to force exactly 2 blocks/CU (3rd block would skew
// makespan 1.5x). glds staging with rotation swizzle (chunk (c+r)&mask) kills
// the stride-0-mod-32-banks conflicts of round 3 while keeping lane-contiguous
// glds destinations.
__global__ __launch_bounds__(256, 2) void attn_kernel(
    const bf16* __restrict__ Q, const bf16* __restrict__ K,
    const bf16* __restrict__ Vt, bf16* __restrict__ Y) {
  const int j = blockIdx.x;          // 0..15
  const int bh = blockIdx.y;
  __shared__ __align__(16) char smem[54528];
  auto Ks  = (bf16(*)[128])smem;               // [64][128]  16384 B (swizzled)
  auto Vts = (bf16(*)[64])(smem + 16384);      // [128][64]  16384 B (swizzled)
  auto Ps  = (bf16(*)[16][72])(smem + 32768);  // [4][16][72] 9216 B (padded)
  // bytes 41984..54528: dead filler to pin occupancy at 2 blocks/CU
  const int tid = threadIdx.x;
  const int wave = tid >> 6;
  const int lane = tid & 63;
  const int quad = lane >> 4;
  const int l16 = lane & 15;

  const bf16* Kbh = K + (size_t)bh * SEQ * HD;
  const bf16* Vbh = Vt + (size_t)bh * HD * SEQ;
  const int b = bh >> 4, h = bh & 15;

  // staging coords (rotation swizzle):
  // K: instr covers 4 rows x 16 chunks; lane -> (row lane>>4, phys chunk lane&15)
  const int krow = lane >> 4;
  // V: instr covers 8 rows x 8 chunks; lane -> (row lane>>3, phys chunk lane&7)
  const int vrow = lane >> 3;
  const int vchunk = ((lane & 7) - vrow) & 7;    // logical chunk, i-invariant

  for (int pass = 0; pass < 2; ++pass) {
    const int qt = pass ? (31 - j) : j;
    const int q0 = qt * 64;
    const int ntiles = qt + 1;

    // Q fragments (B-operand) in registers; q = wave*16 + l16
    const bf16* Qw = Q + ((size_t)bh * SEQ + q0 + wave * 16) * HD;
    bf16x8 qf[4];
#pragma unroll
    for (int kk = 0; kk < 4; kk++)
      qf[kk] = *reinterpret_cast<const bf16x8*>(&Qw[(size_t)l16 * HD + kk * 32 + quad * 8]);

    f32x4 oacc[8] = {};
    float m_i = -3.0e38f, l_i = 0.f;

    for (int t = 0; t < ntiles; ++t) {
      const int kt = t * 64;
      // ---- stage K (64x128) swizzled ----
#pragma unroll
      for (int i = 0; i < 4; i++) {
        const int rbase = wave * 16 + i * 4;
        const int r = rbase + krow;
        const int c = ((lane & 15) - krow - i * 4) & 15;   // logical chunk
        __builtin_amdgcn_global_load_lds(
            GLOBAL_AS(&Kbh[(size_t)(kt + r) * HD + c * 8]), LDS_AS(&Ks[rbase][0]), 16, 0, 0);
      }
      // ---- stage Vt (128x64) swizzled ----
#pragma unroll
      for (int i = 0; i < 4; i++) {
        const int rbase = wave * 32 + i * 8;
        const int r = rbase + vrow;
        __builtin_amdgcn_global_load_lds(
            GLOBAL_AS(&Vbh[(size_t)r * SEQ + kt + vchunk * 8]), LDS_AS(&Vts[rbase][0]), 16, 0, 0);
      }
      __syncthreads();

      // ---- S^T = K Q^T ; swizzled Ks read: chunk (kk*4+quad+l16)&15 ----
      f32x4 sacc[4] = {};
#pragma unroll
      for (int kk = 0; kk < 4; kk++) {
        const int kcol = (((kk * 4 + quad + l16) & 15)) * 8;
        bf16x8 ka[4];
#pragma unroll
        for (int mt = 0; mt < 4; mt++)
          ka[mt] = *reinterpret_cast<const bf16x8*>(&Ks[mt * 16 + l16][kcol]);
#pragma unroll
        for (int mt = 0; mt < 4; mt++)
          sacc[mt] = __builtin_amdgcn_mfma_f32_16x16x32_bf16(ka[mt], qf[kk], sacc[mt], 0, 0, 0);
      }

      // ---- online softmax; lane's column = q = wave*16+l16 ----
      const int qg_loc = wave * 16 + l16;
      float mx = -3.0e38f;
      if (t == ntiles - 1) {   // diagonal tile (kt == q0): causal mask
#pragma unroll
        for (int mt = 0; mt < 4; mt++)
#pragma unroll
          for (int jj = 0; jj < 4; jj++) {
            const int kg = mt * 16 + quad * 4 + jj;
            float v = (kg <= qg_loc) ? sacc[mt][jj] : -3.0e38f;
            sacc[mt][jj] = v;
            mx = fmaxf(mx, v);
          }
      } else {
#pragma unroll
        for (int mt = 0; mt < 4; mt++)
#pragma unroll
          for (int jj = 0; jj < 4; jj++) mx = fmaxf(mx, sacc[mt][jj]);
      }
      mx = fmaxf(mx, __shfl_xor(mx, 16));
      mx = fmaxf(mx, __shfl_xor(mx, 32));
      const float mnew = fmaxf(m_i, mx);
      const float alpha = __expf(m_i - mnew);
      m_i = mnew;
      float rs = 0.f;
#pragma unroll
      for (int mt = 0; mt < 4; mt++)
#pragma unroll
        for (int jj = 0; jj < 4; jj++) {
          float p = __expf(sacc[mt][jj] - mnew);
          sacc[mt][jj] = p;
          rs += p;
        }
      rs += __shfl_xor(rs, 16);
      rs += __shfl_xor(rs, 32);
      l_i = l_i * alpha + rs;
#pragma unroll
      for (int mt8 = 0; mt8 < 8; mt8++)
#pragma unroll
        for (int jj = 0; jj < 4; jj++) oacc[mt8][jj] *= alpha;

      // ---- P^T -> per-wave padded LDS (B-operand layout Ps[q][key]) ----
#pragma unroll
      for (int mt = 0; mt < 4; mt++) {
        bf16x4 pk;
#pragma unroll
        for (int jj = 0; jj < 4; jj++) pk[jj] = (bf16)sacc[mt][jj];
        *reinterpret_cast<bf16x4*>(&Ps[wave][l16][mt * 16 + quad * 4]) = pk;
      }

      // ---- O^T += V^T P^T ; swizzled Vts read: chunk (kk2*4+quad+l16)&7 ----
#pragma unroll
      for (int kk2 = 0; kk2 < 2; kk2++) {
        const int vcol = ((kk2 * 4 + quad + l16) & 7) * 8;
        bf16x8 pb = *reinterpret_cast<const bf16x8*>(&Ps[wave][l16][kk2 * 32 + quad * 8]);
#pragma unroll
        for (int mt8 = 0; mt8 < 8; mt8++) {
          bf16x8 av = *reinterpret_cast<const bf16x8*>(&Vts[mt8 * 16 + l16][vcol]);
          oacc[mt8] = __builtin_amdgcn_mfma_f32_16x16x32_bf16(av, pb, oacc[mt8], 0, 0, 0);
        }
      }
      __syncthreads();   // all waves done with Ks/Vts before restage
    }

    // ---- epilogue: O^T/l -> Y[b][s][h*128+d] ----
    const float inv = 1.0f / l_i;
    const int qg = q0 + wave * 16 + l16;
#pragma unroll
    for (int mt8 = 0; mt8 < 8; mt8++) {
      bf16x4 pk;
#pragma unroll
      for (int jj = 0; jj < 4; jj++) pk[jj] = (bf16)(oacc[mt8][jj] * inv);
      *reinterpret_cast<bf16x4*>(
          &Y[(size_t)(b * SEQ + qg) * DMODEL + h * HD + mt8 * 16 + quad * 4]) = pk;
    }
  }
}

// ---------------- launch ----------------
extern "C" void kernel_launch(void* const* d_in, const int* in_sizes, int n_in,
                              void* d_out, int out_size, void* d_ws, size_t ws_size,
                              hipStream_t stream) {
  const float* x  = (const float*)d_in[0];
  const float* Wq = (const float*)d_in[2];
  const float* Wk = (const float*)d_in[3];
  const float* Wv = (const float*)d_in[4];
  const float* Wo = (const float*)d_in[5];
  float* out = (float*)d_out;

  char* ws = (char*)d_ws;
  bf16* xb  = (bf16*)(ws + 0);
  bf16* Wqb = (bf16*)(ws + 16777216);    // Wq,Wk,Wv contiguous -> one [6144][2048]
  bf16* Wkb = (bf16*)(ws + 25165824);
  bf16* Wvb = (bf16*)(ws + 33554432);
  bf16* Wob = (bf16*)(ws + 41943040);
  bf16* Qb  = (bf16*)(ws + 50331648);    // [B,H,S,d]
  bf16* Kb  = (bf16*)(ws + 67108864);    // [B,H,S,d]
  bf16* Vtb = (bf16*)(ws + 83886080);    // [B,H,d,S]
  bf16* Yb  = xb;                        // [B,S,D] (x dead after projections)
  if (ws_size < 100663296) return;

  const int nx4 = MROWS * DMODEL / 4;
  const int nw4 = DMODEL * DMODEL / 4;
  cvt_kernel<<<nx4 / 256, 256, 0, stream>>>(x, xb, nx4);
  cvt_kernel<<<nw4 / 256, 256, 0, stream>>>(Wq, Wqb, nw4);
  cvt_kernel<<<nw4 / 256, 256, 0, stream>>>(Wk, Wkb, nw4);
  cvt_kernel<<<nw4 / 256, 256, 0, stream>>>(Wv, Wvb, nw4);
  cvt_kernel<<<nw4 / 256, 256, 0, stream>>>(Wo, Wob, nw4);

  gemm_bt<MODE_QKV><<<dim3(48, MROWS / 128), 256, 0, stream>>>(
      xb, Wqb, Qb, Kb, Vtb, nullptr);

  attn_kernel<<<dim3(16, BATCH * NH), 256, 0, stream>>>(Qb, Kb, Vtb, Yb);

  gemm_bt<MODE_OUT><<<dim3(16, MROWS / 128), 256, 0, stream>>>(
      Yb, Wob, nullptr, nullptr, nullptr, out);
}

// Round 6
// 362.417 us; speedup vs baseline: 1.4686x; 1.0948x over previous
//
#include <hip/hip_runtime.h>
#include <hip/hip_bf16.h>
#include <cstdint>
#include <cstddef>

typedef __bf16 bf16;
typedef __bf16 bf16x8 __attribute__((ext_vector_type(8)));
typedef __bf16 bf16x4 __attribute__((ext_vector_type(4)));
typedef float f32x4 __attribute__((ext_vector_type(4)));

static constexpr int BATCH = 2;
static constexpr int SEQ = 2048;
static constexpr int DMODEL = 2048;
static constexpr int NH = 16;
static constexpr int HD = 128;
static constexpr int MROWS = BATCH * SEQ; // 4096

#define GLOBAL_AS(p) ((const __attribute__((address_space(1))) void*)(p))
#define LDS_AS(p)    ((__attribute__((address_space(3))) void*)(p))

// ---------------- fused fp32 -> bf16 convert (x, Wq, Wk, Wv, Wo in one launch) ----
// float4-group counts: x = 2,097,152 ; each W = 1,048,576 ; total 6,291,456.
// dst regions are contiguous: xb | Wq | Wk | Wv | Wo.
__global__ void cvt5_kernel(const float* __restrict__ x,
                            const float* __restrict__ wq, const float* __restrict__ wk,
                            const float* __restrict__ wv, const float* __restrict__ wo,
                            bf16* __restrict__ dst) {
  const int i = blockIdx.x * blockDim.x + threadIdx.x;   // global float4 index
  const float* src;
  int local;
  if (i < 2097152) { src = x; local = i; }
  else {
    const int r = i - 2097152;
    const int w = r >> 20;            // 0..3 (block-uniform: 4096 blocks per weight)
    local = r & 1048575;
    src = (w == 0) ? wq : (w == 1) ? wk : (w == 2) ? wv : wo;
  }
  float4 f = reinterpret_cast<const float4*>(src)[local];
  bf16x4 o;
  o.x = (bf16)f.x; o.y = (bf16)f.y; o.z = (bf16)f.z; o.w = (bf16)f.w;
  reinterpret_cast<bf16x4*>(dst)[i] = o;
}

// ---------------- GEMM: C = A(MxK,row) * W(NxK,row)^T ----------------
// m97 structure + rotation swizzle: row r's 16B-chunk c stored at chunk (c+r)&7.
// glds covers 8 rows x 8 chunks per 1KB instr, rbase%8==0 -> lane permutation
// is i-invariant. Fragment read chunk = (ks*4+quad+l16)&7 -> 2-way banks (free).
enum { MODE_QKV = 0, MODE_OUT = 1 };

template <int MODE>
__global__ __launch_bounds__(256, 4) void gemm_bt(
    const bf16* __restrict__ A, const bf16* __restrict__ W,
    bf16* __restrict__ Oq, bf16* __restrict__ Ok, bf16* __restrict__ Ov,
    float* __restrict__ Oout) {
  constexpr int Kd = DMODEL;
  __shared__ __align__(16) bf16 As[128][64];
  __shared__ __align__(16) bf16 Bs[128][64];
  const int n0 = blockIdx.x * 128;
  const int m0 = blockIdx.y * 128;
  const int tid = threadIdx.x;
  const int wave = tid >> 6;
  const int lane = tid & 63;
  const int quad = lane >> 4;
  const int l16 = lane & 15;
  const int wm = (wave >> 1) * 64;
  const int wn = (wave & 1) * 64;
  const int srow = lane >> 3;                       // 0..7 within the 8-row chunk
  const int schunk = ((lane & 7) - srow) & 7;       // logical 16B chunk (swizzle src)

  f32x4 acc[4][4] = {};
  for (int kt = 0; kt < Kd; kt += 64) {
#pragma unroll
    for (int i = 0; i < 4; i++) {
      const int r = wave * 32 + i * 8;              // r % 8 == 0
      __builtin_amdgcn_global_load_lds(
          GLOBAL_AS(&A[(size_t)(m0 + r + srow) * Kd + kt + schunk * 8]),
          LDS_AS(&As[r][0]), 16, 0, 0);
      __builtin_amdgcn_global_load_lds(
          GLOBAL_AS(&W[(size_t)(n0 + r + srow) * Kd + kt + schunk * 8]),
          LDS_AS(&Bs[r][0]), 16, 0, 0);
    }
    __syncthreads();
#pragma unroll
    for (int ks = 0; ks < 2; ks++) {
      const int col = (((ks * 4 + quad + l16) & 7)) * 8;   // swizzled read chunk
      bf16x8 af[4], bfr[4];
#pragma unroll
      for (int t = 0; t < 4; t++)
        af[t] = *reinterpret_cast<const bf16x8*>(&As[wm + t * 16 + l16][col]);
#pragma unroll
      for (int t = 0; t < 4; t++)
        bfr[t] = *reinterpret_cast<const bf16x8*>(&Bs[wn + t * 16 + l16][col]);
#pragma unroll
      for (int tm = 0; tm < 4; tm++)
#pragma unroll
        for (int tn = 0; tn < 4; tn++)
          acc[tm][tn] = __builtin_amdgcn_mfma_f32_16x16x32_bf16(af[tm], bfr[tn], acc[tm][tn], 0, 0, 0);
    }
    __syncthreads();
  }
#pragma unroll
  for (int tm = 0; tm < 4; tm++) {
#pragma unroll
    for (int tn = 0; tn < 4; tn++) {
      const int row0 = m0 + wm + tm * 16 + quad * 4;
      if constexpr (MODE == MODE_OUT) {
        const int col = n0 + wn + tn * 16 + l16;
#pragma unroll
        for (int j = 0; j < 4; j++)
          Oout[(size_t)(row0 + j) * DMODEL + col] = acc[tm][tn][j];
      } else {
        const int mat = n0 >> 11;              // 0=Q 1=K 2=V
        const int col = (n0 & 2047) + wn + tn * 16 + l16;
        const int h = col >> 7, dd = col & 127;
        if (mat == 2) {
          const int b = row0 >> 11, s = row0 & 2047;
          bf16x4 pk;
#pragma unroll
          for (int j = 0; j < 4; j++) pk[j] = (bf16)acc[tm][tn][j];
          *reinterpret_cast<bf16x4*>(&Ov[((size_t)(b * NH + h) * HD + dd) * SEQ + s]) = pk;
        } else {
          bf16* O = mat ? Ok : Oq;
          const float scale = mat ? 1.0f : 0.08838834764831845f;
#pragma unroll
          for (int j = 0; j < 4; j++) {
            const int row = row0 + j;
            const int b = row >> 11, s = row & 2047;
            O[((size_t)(b * NH + h) * SEQ + s) * HD + dd] = (bf16)(acc[tm][tn][j] * scale);
          }
        }
      }
    }
  }
}

// ---------------- flash attention (unchanged from round 4) ----------------
__global__ __launch_bounds__(256, 2) void attn_kernel(
    const bf16* __restrict__ Q, const bf16* __restrict__ K,
    const bf16* __restrict__ Vt, bf16* __restrict__ Y) {
  const int j = blockIdx.x;          // 0..15
  const int bh = blockIdx.y;
  __shared__ __align__(16) char smem[54528];
  auto Ks  = (bf16(*)[128])smem;               // [64][128]  16384 B (swizzled)
  auto Vts = (bf16(*)[64])(smem + 16384);      // [128][64]  16384 B (swizzled)
  auto Ps  = (bf16(*)[16][72])(smem + 32768);  // [4][16][72] 9216 B (padded)
  const int tid = threadIdx.x;
  const int wave = tid >> 6;
  const int lane = tid & 63;
  const int quad = lane >> 4;
  const int l16 = lane & 15;

  const bf16* Kbh = K + (size_t)bh * SEQ * HD;
  const bf16* Vbh = Vt + (size_t)bh * HD * SEQ;
  const int b = bh >> 4, h = bh & 15;

  const int krow = lane >> 4;
  const int vrow = lane >> 3;
  const int vchunk = ((lane & 7) - vrow) & 7;

  for (int pass = 0; pass < 2; ++pass) {
    const int qt = pass ? (31 - j) : j;
    const int q0 = qt * 64;
    const int ntiles = qt + 1;

    const bf16* Qw = Q + ((size_t)bh * SEQ + q0 + wave * 16) * HD;
    bf16x8 qf[4];
#pragma unroll
    for (int kk = 0; kk < 4; kk++)
      qf[kk] = *reinterpret_cast<const bf16x8*>(&Qw[(size_t)l16 * HD + kk * 32 + quad * 8]);

    f32x4 oacc[8] = {};
    float m_i = -3.0e38f, l_i = 0.f;

    for (int t = 0; t < ntiles; ++t) {
      const int kt = t * 64;
#pragma unroll
      for (int i = 0; i < 4; i++) {
        const int rbase = wave * 16 + i * 4;
        const int r = rbase + krow;
        const int c = ((lane & 15) - krow - i * 4) & 15;
        __builtin_amdgcn_global_load_lds(
            GLOBAL_AS(&Kbh[(size_t)(kt + r) * HD + c * 8]), LDS_AS(&Ks[rbase][0]), 16, 0, 0);
      }
#pragma unroll
      for (int i = 0; i < 4; i++) {
        const int rbase = wave * 32 + i * 8;
        const int r = rbase + vrow;
        __builtin_amdgcn_global_load_lds(
            GLOBAL_AS(&Vbh[(size_t)r * SEQ + kt + vchunk * 8]), LDS_AS(&Vts[rbase][0]), 16, 0, 0);
      }
      __syncthreads();

      f32x4 sacc[4] = {};
#pragma unroll
      for (int kk = 0; kk < 4; kk++) {
        const int kcol = (((kk * 4 + quad + l16) & 15)) * 8;
        bf16x8 ka[4];
#pragma unroll
        for (int mt = 0; mt < 4; mt++)
          ka[mt] = *reinterpret_cast<const bf16x8*>(&Ks[mt * 16 + l16][kcol]);
#pragma unroll
        for (int mt = 0; mt < 4; mt++)
          sacc[mt] = __builtin_amdgcn_mfma_f32_16x16x32_bf16(ka[mt], qf[kk], sacc[mt], 0, 0, 0);
      }

      const int qg_loc = wave * 16 + l16;
      float mx = -3.0e38f;
      if (t == ntiles - 1) {
#pragma unroll
        for (int mt = 0; mt < 4; mt++)
#pragma unroll
          for (int jj = 0; jj < 4; jj++) {
            const int kg = mt * 16 + quad * 4 + jj;
            float v = (kg <= qg_loc) ? sacc[mt][jj] : -3.0e38f;
            sacc[mt][jj] = v;
            mx = fmaxf(mx, v);
          }
      } else {
#pragma unroll
        for (int mt = 0; mt < 4; mt++)
#pragma unroll
          for (int jj = 0; jj < 4; jj++) mx = fmaxf(mx, sacc[mt][jj]);
      }
      mx = fmaxf(mx, __shfl_xor(mx, 16));
      mx = fmaxf(mx, __shfl_xor(mx, 32));
      const float mnew = fmaxf(m_i, mx);
      const float alpha = __expf(m_i - mnew);
      m_i = mnew;
      float rs = 0.f;
#pragma unroll
      for (int mt = 0; mt < 4; mt++)
#pragma unroll
        for (int jj = 0; jj < 4; jj++) {
          float p = __expf(sacc[mt][jj] - mnew);
          sacc[mt][jj] = p;
          rs += p;
        }
      rs += __shfl_xor(rs, 16);
      rs += __shfl_xor(rs, 32);
      l_i = l_i * alpha + rs;
#pragma unroll
      for (int mt8 = 0; mt8 < 8; mt8++)
#pragma unroll
        for (int jj = 0; jj < 4; jj++) oacc[mt8][jj] *= alpha;

#pragma unroll
      for (int mt = 0; mt < 4; mt++) {
        bf16x4 pk;
#pragma unroll
        for (int jj = 0; jj < 4; jj++) pk[jj] = (bf16)sacc[mt][jj];
        *reinterpret_cast<bf16x4*>(&Ps[wave][l16][mt * 16 + quad * 4]) = pk;
      }

#pragma unroll
      for (int kk2 = 0; kk2 < 2; kk2++) {
        const int vcol = ((kk2 * 4 + quad + l16) & 7) * 8;
        bf16x8 pb = *reinterpret_cast<const bf16x8*>(&Ps[wave][l16][kk2 * 32 + quad * 8]);
#pragma unroll
        for (int mt8 = 0; mt8 < 8; mt8++) {
          bf16x8 av = *reinterpret_cast<const bf16x8*>(&Vts[mt8 * 16 + l16][vcol]);
          oacc[mt8] = __builtin_amdgcn_mfma_f32_16x16x32_bf16(av, pb, oacc[mt8], 0, 0, 0);
        }
      }
      __syncthreads();
    }

    const float inv = 1.0f / l_i;
    const int qg = q0 + wave * 16 + l16;
#pragma unroll
    for (int mt8 = 0; mt8 < 8; mt8++) {
      bf16x4 pk;
#pragma unroll
      for (int jj = 0; jj < 4; jj++) pk[jj] = (bf16)(oacc[mt8][jj] * inv);
      *reinterpret_cast<bf16x4*>(
          &Y[(size_t)(b * SEQ + qg) * DMODEL + h * HD + mt8 * 16 + quad * 4]) = pk;
    }
  }
}

// ---------------- launch ----------------
extern "C" void kernel_launch(void* const* d_in, const int* in_sizes, int n_in,
                              void* d_out, int out_size, void* d_ws, size_t ws_size,
                              hipStream_t stream) {
  const float* x  = (const float*)d_in[0];
  const float* Wq = (const float*)d_in[2];
  const float* Wk = (const float*)d_in[3];
  const float* Wv = (const float*)d_in[4];
  const float* Wo = (const float*)d_in[5];
  float* out = (float*)d_out;

  char* ws = (char*)d_ws;
  bf16* xb  = (bf16*)(ws + 0);
  bf16* Wqb = (bf16*)(ws + 16777216);    // Wq,Wk,Wv contiguous -> one [6144][2048]
  bf16* Wob = (bf16*)(ws + 41943040);
  bf16* Qb  = (bf16*)(ws + 50331648);    // [B,H,S,d]
  bf16* Kb  = (bf16*)(ws + 67108864);    // [B,H,S,d]
  bf16* Vtb = (bf16*)(ws + 83886080);    // [B,H,d,S]
  bf16* Yb  = xb;                        // [B,S,D] (x dead after projections)
  if (ws_size < 100663296) return;

  // one fused convert: 6,291,456 float4 groups -> 24576 blocks
  cvt5_kernel<<<24576, 256, 0, stream>>>(x, Wq, Wk, Wv, Wo, xb);

  gemm_bt<MODE_QKV><<<dim3(48, MROWS / 128), 256, 0, stream>>>(
      xb, Wqb, Qb, Kb, Vtb, nullptr);

  attn_kernel<<<dim3(16, BATCH * NH), 256, 0, stream>>>(Qb, Kb, Vtb, Yb);

  gemm_bt<MODE_OUT><<<dim3(16, MROWS / 128), 256, 0, stream>>>(
      Yb, Wob, nullptr, nullptr, nullptr, out);
}